// Round 7
// baseline (73.071 us; speedup 1.0000x reference)
//
#include <hip/hip_runtime.h>

typedef float f2 __attribute__((ext_vector_type(2)));

#define HH 512
#define WW 512
#define NB 32
#define TW 64                    // output tile width (px)
#define TH 16                    // output tile height
#define RB 4                     // rows per thread
#define NT 4                     // tiles per block (vertical walk)
#define TIW (TW + 4)             // 68 (halo 2 each side)
#define TIH (TH + 4)             // 20
#define NTILE (TIW * TIH)        // 1360
#define NSLOT 6                  // ceil(1360/256)
#define TAILT (NTILE - 256 * (NSLOT - 1))  // 80: slot5 valid for t<80
#define EPS 1e-5f

// Wave-uniform loads via constant address space -> s_load (SGPR, SMEM pipe).
__device__ __forceinline__ const __attribute__((address_space(4))) float*
cptr(const float* p) {
    return (const __attribute__((address_space(4))) float*)(unsigned long long)p;
}
__device__ __forceinline__ f2 ldw2(const float* p) {
    const __attribute__((address_space(4))) float* q = cptr(p);
    return f2{q[0], q[1]};
}
__device__ __forceinline__ float ldw1(const float* p) { return cptr(p)[0]; }

__device__ __forceinline__ float4 ldx4(const float* __restrict__ x, int b, int h, int w) {
    return *reinterpret_cast<const float4*>(x + ((((size_t)b * HH + h) * WW + w) << 2));
}

// ---- staging -------------------------------------------------------------
// fast path: pure pointer-relative loads (interior tile, all addrs valid)
// checked path: per-lane bounds + zero fill (W-edge blocks, top/bottom rows)
__device__ __forceinline__ void stage_load(const float* __restrict__ p0,  // &x[b][h0-2][w0p-2]
                                           bool chk, int h0, int w0p, int b,
                                           const float* __restrict__ x,
                                           const int* tr, const int* tc,
                                           const int* goff, int t,
                                           float4 pf[NSLOT]) {
    if (!chk) {
#pragma unroll
        for (int j = 0; j < NSLOT; ++j) {
            if (j == NSLOT - 1 && t >= TAILT) continue;
            pf[j] = *reinterpret_cast<const float4*>(p0 + goff[j]);
        }
    } else {
#pragma unroll
        for (int j = 0; j < NSLOT; ++j) {
            if (j == NSLOT - 1 && t >= TAILT) continue;
            int gr = h0 - 2 + tr[j];
            int gc = w0p - 2 + tc[j];
            float4 v = {0.f, 0.f, 0.f, 0.f};
            if (((unsigned)gr < (unsigned)HH) & ((unsigned)gc < (unsigned)WW))
                v = ldx4(x, b, gr, gc);
            pf[j] = v;
        }
    }
}

__device__ __forceinline__ void stage_write(float4* __restrict__ buf, int t,
                                            const float4 pf[NSLOT]) {
#pragma unroll
    for (int j = 0; j < NSLOT; ++j) {
        if (j == NSLOT - 1 && t >= TAILT) continue;
        buf[t + 256 * j] = pf[j];
    }
}

// ---- conv ----------------------------------------------------------------
template <int K, bool DW>
__device__ __forceinline__ void conv_tile(const float4* __restrict__ tile,  // [TIH][TIW]
                                          const float* __restrict__ wgt,
                                          int tx, int ty,
                                          f2 accl[RB], f2 acch[RB]) {
    constexpr int P = K / 2;
#pragma unroll
    for (int i = 0; i < RB + 2 * P; ++i) {
        const float4* trow = tile + (ty * RB + (2 - P) + i) * TIW + tx + (2 - P);
        float4 win[K];
#pragma unroll
        for (int kj = 0; kj < K; ++kj) win[kj] = trow[kj];
#pragma unroll
        for (int r = 0; r < RB; ++r) {
            int ki = i - r;                       // compile-time per (i,r)
            if (ki < 0 || ki >= K) continue;
#pragma unroll
            for (int kj = 0; kj < K; ++kj) {
                float4 p = win[kj];
                if (DW) {
                    const float* wp = wgt + (ki * K + kj) * 4;   // [c]
                    accl[r] += f2{p.x, p.y} * ldw2(wp + 0);
                    acch[r] += f2{p.z, p.w} * ldw2(wp + 2);
                } else {
                    const float* wp = wgt + (ki * K + kj) * 16;  // [in][out] 4x4
                    accl[r] += p.x * ldw2(wp + 0)  + p.y * ldw2(wp + 4)
                             + p.z * ldw2(wp + 8)  + p.w * ldw2(wp + 12);
                    acch[r] += p.x * ldw2(wp + 2)  + p.y * ldw2(wp + 6)
                             + p.z * ldw2(wp + 10) + p.w * ldw2(wp + 14);
                }
            }
        }
    }
}

// ---- BN epilogue ---------------------------------------------------------
struct BN { f2 ivl, ivh, shl, shh; };

__device__ __forceinline__ BN make_bn(const float* gamma, const float* beta,
                                      const float* mean, const float* var, int idx) {
    const float* ga = gamma + idx * 4;
    const float* be = beta + idx * 4;
    const float* mu = mean + idx * 4;
    const float* vr = var + idx * 4;
    f2 g01 = ldw2(ga + 0), g23 = ldw2(ga + 2);
    f2 v01 = ldw2(vr + 0), v23 = ldw2(vr + 2);
    f2 b01 = ldw2(be + 0), b23 = ldw2(be + 2);
    f2 m01 = ldw2(mu + 0), m23 = ldw2(mu + 2);
    BN bn;
    bn.ivl = f2{g01.x * rsqrtf(v01.x + EPS), g01.y * rsqrtf(v01.y + EPS)};
    bn.ivh = f2{g23.x * rsqrtf(v23.x + EPS), g23.y * rsqrtf(v23.y + EPS)};
    bn.shl = b01 - m01 * bn.ivl;
    bn.shh = b23 - m23 * bn.ivh;
    return bn;
}

__device__ __forceinline__ void bn_store(float* __restrict__ out, const BN& bn,
                                         const f2 accl[RB], const f2 acch[RB],
                                         int b, int h0, int ty, int w0p, int tx) {
#pragma unroll
    for (int r = 0; r < RB; ++r) {
        f2 ol = accl[r] * bn.ivl + bn.shl;
        f2 oh = acch[r] * bn.ivh + bn.shh;
        float4 o;
        o.x = ol.x > 0.f ? ol.x : 0.f;
        o.y = ol.y > 0.f ? ol.y : 0.f;
        o.z = oh.x > 0.f ? oh.x : 0.f;
        o.w = oh.y > 0.f ? oh.y : 0.f;
        *reinterpret_cast<float4*>(
            out + ((((size_t)b * HH + h0 + ty * RB + r) * WW + w0p + tx) << 2)) = o;
    }
}

// ---- one pipeline step: issue loads(i+1) -> conv(i) -> store -> ds_write(i+1)
//      -> single barrier.  vmcnt for the loads ages through the whole conv.
template <int K, bool DW>
__device__ __forceinline__ void tile_step(const float* __restrict__ x,
                                          float* __restrict__ out,
                                          const float* __restrict__ wgt,
                                          const BN& bn,
                                          const float4* bufC, float4* bufS,
                                          int i, int b, int h0b, int w0p,
                                          const int* tr, const int* tc,
                                          const int* goff, int t, int tx, int ty,
                                          bool wchk) {
    int h0 = h0b + i * TH;
    float4 pf[NSLOT];
    bool last = (i == NT - 1);
    if (!last) {
        int h1 = h0 + TH;
        bool chk = wchk | (h1 + TIH - 3 >= HH);          // bottom rows OOB
        const float* p1 = x + (((size_t)b * HH + (h1 - 2)) * WW + (w0p - 2)) * 4;
        stage_load(p1, chk, h1, w0p, b, x, tr, tc, goff, t, pf);
    }
    f2 accl[RB] = {f2{0.f,0.f}, f2{0.f,0.f}, f2{0.f,0.f}, f2{0.f,0.f}};
    f2 acch[RB] = {f2{0.f,0.f}, f2{0.f,0.f}, f2{0.f,0.f}, f2{0.f,0.f}};
    conv_tile<K, DW>(bufC, wgt, tx, ty, accl, acch);
    bn_store(out, bn, accl, acch, b, h0, ty, w0p, tx);
    if (!last) stage_write(bufS, t, pf);
    __syncthreads();
}

template <int K, bool DW>
__device__ __forceinline__ void run_tiles(const float* __restrict__ x,
                                          float* __restrict__ out,
                                          const float* __restrict__ wgt,
                                          const BN& bn,
                                          float4* buf0, float4* buf1,
                                          int b, int h0b, int w0p,
                                          const int* tr, const int* tc,
                                          const int* goff, int t, int tx, int ty,
                                          bool wchk) {
    // prologue: stage tile 0 into buf0
    {
        float4 pf[NSLOT];
        bool chk = wchk | (h0b == 0);
        const float* p0 = x + (((size_t)b * HH + (h0b - 2)) * WW + (w0p - 2)) * 4;
        stage_load(p0, chk, h0b, w0p, b, x, tr, tc, goff, t, pf);
        stage_write(buf0, t, pf);
        __syncthreads();
    }
#pragma unroll 1
    for (int i = 0; i < NT; i += 2) {
        tile_step<K, DW>(x, out, wgt, bn, buf0, buf1, i,     b, h0b, w0p,
                         tr, tc, goff, t, tx, ty, wchk);
        tile_step<K, DW>(x, out, wgt, bn, buf1, buf0, i + 1, b, h0b, w0p,
                         tr, tc, goff, t, tx, ty, wchk);
    }
}

__global__ __launch_bounds__(256, 3) void mixop_kernel(
    const float* __restrict__ x,
    const float* __restrict__ logits, const float* __restrict__ g,
    const float* __restrict__ w0, const float* __restrict__ w1,
    const float* __restrict__ w2, const float* __restrict__ w3,
    const float* __restrict__ w4,
    const float* __restrict__ gamma, const float* __restrict__ beta,
    const float* __restrict__ mean, const float* __restrict__ var,
    float* __restrict__ out) {
    __shared__ float4 tile[2][NTILE];    // 43.5 KB double buffer

    int t   = threadIdx.x;
    int blk = blockIdx.x;
    int bw  = blk & 7;             // WW/TW = 8
    int hg  = (blk >> 3) & 7;      // HH/(TH*NT) = 8
    int b   = blk >> 6;            // batch
    int w0p = bw * TW;
    int h0b = hg * (TH * NT);
    bool wchk = (bw == 0) | (bw == 7);

    // wave-uniform routing: argmax(logits + g), first-max wins (s_load inputs)
    int idx = 0;
    float best = ldw1(logits + 0) + ldw1(g + 0);
#pragma unroll
    for (int i = 1; i < 5; ++i) {
        float v = ldw1(logits + i) + ldw1(g + i);
        if (v > best) { best = v; idx = i; }
    }

    int tx = t & 63;               // lane-consecutive w -> coalesced I/O
    int ty = t >> 6;

    BN bn = make_bn(gamma, beta, mean, var, idx);

    if (idx == 0) {
        // 1x1 conv: no reuse -> direct global reads, no LDS/barriers
        f2 a0 = ldw2(w0 + 0),  c0 = ldw2(w0 + 2);
        f2 a1 = ldw2(w0 + 4),  c1 = ldw2(w0 + 6);
        f2 a2 = ldw2(w0 + 8),  c2 = ldw2(w0 + 10);
        f2 a3 = ldw2(w0 + 12), c3 = ldw2(w0 + 14);
#pragma unroll 1
        for (int i = 0; i < NT; ++i) {
            int h0 = h0b + i * TH;
            f2 accl[RB], acch[RB];
#pragma unroll
            for (int r = 0; r < RB; ++r) {
                float4 p = ldx4(x, b, h0 + ty * RB + r, w0p + tx);
                accl[r] = p.x * a0 + p.y * a1 + p.z * a2 + p.w * a3;
                acch[r] = p.x * c0 + p.y * c1 + p.z * c2 + p.w * c3;
            }
            bn_store(out, bn, accl, acch, b, h0, ty, w0p, tx);
        }
        return;
    }

    // per-thread staging coords + relative byte offsets, computed once
    int tr[NSLOT], tc[NSLOT], goff[NSLOT];
#pragma unroll
    for (int j = 0; j < NSLOT; ++j) {
        int k = t + 256 * j;
        tr[j] = k / TIW;
        tc[j] = k - tr[j] * TIW;
        goff[j] = (tr[j] * WW + tc[j]) * 4;      // floats rel. to &x[h0-2][w0p-2]
    }

    switch (idx) {
        case 1: run_tiles<3, false>(x, out, w1, bn, tile[0], tile[1], b, h0b, w0p,
                                    tr, tc, goff, t, tx, ty, wchk); break;
        case 2: run_tiles<3, true >(x, out, w2, bn, tile[0], tile[1], b, h0b, w0p,
                                    tr, tc, goff, t, tx, ty, wchk); break;
        case 3: run_tiles<5, false>(x, out, w3, bn, tile[0], tile[1], b, h0b, w0p,
                                    tr, tc, goff, t, tx, ty, wchk); break;
        case 4: run_tiles<5, true >(x, out, w4, bn, tile[0], tile[1], b, h0b, w0p,
                                    tr, tc, goff, t, tx, ty, wchk); break;
    }
}

extern "C" void kernel_launch(void* const* d_in, const int* in_sizes, int n_in,
                              void* d_out, int out_size, void* d_ws, size_t ws_size,
                              hipStream_t stream) {
    const float* x      = (const float*)d_in[0];
    const float* logits = (const float*)d_in[1];
    const float* g      = (const float*)d_in[2];
    const float* w0     = (const float*)d_in[3];
    const float* w1     = (const float*)d_in[4];
    const float* w2     = (const float*)d_in[5];
    const float* w3     = (const float*)d_in[6];
    const float* w4     = (const float*)d_in[7];
    const float* gamma  = (const float*)d_in[8];
    const float* beta   = (const float*)d_in[9];
    const float* mean   = (const float*)d_in[10];
    const float* var    = (const float*)d_in[11];
    float* out = (float*)d_out;

    const int blocks = NB * 8 * (HH / (TH * NT));  // 32*8*8 = 2048
    mixop_kernel<<<blocks, 256, 0, stream>>>(
        x, logits, g, w0, w1, w2, w3, w4, gamma, beta, mean, var, out);
}

// Round 8
// 69.424 us; speedup vs baseline: 1.0525x; 1.0525x over previous
//
#include <hip/hip_runtime.h>

typedef float f2 __attribute__((ext_vector_type(2)));

#define HH 512
#define WW 512
#define NB 32
#define TW 64                    // output tile width (px)
#define TH 16                    // output tile height
#define RB 4                     // rows per thread (ty 0..3 -> rows 4ty..4ty+3)
#define NT 8                     // tiles per block (vertical walk)
#define TIW (TW + 4)             // 68 (halo P<=2 each side)
#define TIH (TH + 4)             // 20
#define NTILE (TIW * TIH)        // 1360
#define NSLOT 6                  // ceil(1360/256)
#define EPS 1e-5f

// Wave-uniform loads routed through constant address space -> s_load (SGPR).
__device__ __forceinline__ const __attribute__((address_space(4))) float*
cptr(const float* p) {
    return (const __attribute__((address_space(4))) float*)(unsigned long long)p;
}
__device__ __forceinline__ f2 ldw2(const float* p) {
    const __attribute__((address_space(4))) float* q = cptr(p);
    return f2{q[0], q[1]};
}
__device__ __forceinline__ float ldw1(const float* p) { return cptr(p)[0]; }

// guaranteed packed math: llvm.fma.v2f32 -> v_pk_fma_f32 (VOP3P).
__device__ __forceinline__ f2 pkfma(f2 a, f2 b, f2 c) {
    return __builtin_elementwise_fma(a, b, c);
}
__device__ __forceinline__ f2 splat(float v) { return f2{v, v}; }

__device__ __forceinline__ float4 ldx4(const float* __restrict__ x, int b, int h, int w) {
    return *reinterpret_cast<const float4*>(x + ((((size_t)b * HH + h) * WW + w) << 2));
}

// issue the 6-slot register prefetch for the tile at (b, h0, w0p)
__device__ __forceinline__ void load_pf(const float* __restrict__ x, int b, int h0,
                                        int w0p, const int* tr, const int* tc,
                                        int t, float4 pf[NSLOT]) {
#pragma unroll
    for (int j = 0; j < NSLOT; ++j) {
        if (j == NSLOT - 1 && t >= NTILE - 256 * (NSLOT - 1)) continue;  // slot invalid
        int gr = h0 - 2 + tr[j];
        int gc = w0p - 2 + tc[j];
        float4 v = {0.f, 0.f, 0.f, 0.f};
        if (((unsigned)gr < (unsigned)HH) & ((unsigned)gc < (unsigned)WW))
            v = ldx4(x, b, gr, gc);
        pf[j] = v;
    }
}

// compute RB vertical output px from the staged tile; weights HWIO (SGPR loads)
template <int K, bool DW>
__device__ __forceinline__ void conv_tile(const float4* __restrict__ tile,  // [TIH][TIW]
                                          const float* __restrict__ wgt,
                                          int tx, int ty,
                                          f2 accl[RB], f2 acch[RB]) {
    constexpr int P = K / 2;
#pragma unroll
    for (int i = 0; i < RB + 2 * P; ++i) {
        const float4* trow = tile + (ty * RB + (2 - P) + i) * TIW + tx + (2 - P);
        float4 win[K];
#pragma unroll
        for (int kj = 0; kj < K; ++kj) win[kj] = trow[kj];
#pragma unroll
        for (int r = 0; r < RB; ++r) {
            int ki = i - r;                       // compile-time per (i,r)
            if (ki < 0 || ki >= K) continue;
#pragma unroll
            for (int kj = 0; kj < K; ++kj) {
                float4 p = win[kj];
                if (DW) {
                    const float* wp = wgt + (ki * K + kj) * 4;   // [c]
                    accl[r] = pkfma(f2{p.x, p.y}, ldw2(wp + 0), accl[r]);
                    acch[r] = pkfma(f2{p.z, p.w}, ldw2(wp + 2), acch[r]);
                } else {
                    const float* wp = wgt + (ki * K + kj) * 16;  // [in][out] 4x4
                    f2 px = splat(p.x), py = splat(p.y);
                    f2 pz = splat(p.z), pw = splat(p.w);
                    accl[r] = pkfma(px, ldw2(wp + 0),  accl[r]);
                    accl[r] = pkfma(py, ldw2(wp + 4),  accl[r]);
                    accl[r] = pkfma(pz, ldw2(wp + 8),  accl[r]);
                    accl[r] = pkfma(pw, ldw2(wp + 12), accl[r]);
                    acch[r] = pkfma(px, ldw2(wp + 2),  acch[r]);
                    acch[r] = pkfma(py, ldw2(wp + 6),  acch[r]);
                    acch[r] = pkfma(pz, ldw2(wp + 10), acch[r]);
                    acch[r] = pkfma(pw, ldw2(wp + 14), acch[r]);
                }
            }
        }
    }
}

struct BN { f2 ivl, ivh, shl, shh; };

__device__ __forceinline__ BN make_bn(const float* gamma, const float* beta,
                                      const float* mean, const float* var, int idx) {
    const float* ga = gamma + idx * 4;
    const float* be = beta + idx * 4;
    const float* mu = mean + idx * 4;
    const float* vr = var + idx * 4;
    f2 g01 = ldw2(ga + 0), g23 = ldw2(ga + 2);
    f2 v01 = ldw2(vr + 0), v23 = ldw2(vr + 2);
    f2 b01 = ldw2(be + 0), b23 = ldw2(be + 2);
    f2 m01 = ldw2(mu + 0), m23 = ldw2(mu + 2);
    BN bn;
    bn.ivl = f2{g01.x * rsqrtf(v01.x + EPS), g01.y * rsqrtf(v01.y + EPS)};
    bn.ivh = f2{g23.x * rsqrtf(v23.x + EPS), g23.y * rsqrtf(v23.y + EPS)};
    bn.shl = b01 - m01 * bn.ivl;
    bn.shh = b23 - m23 * bn.ivh;
    return bn;
}

__device__ __forceinline__ void bn_store(float* __restrict__ out, const BN& bn,
                                         const f2 accl[RB], const f2 acch[RB],
                                         int b, int h0, int ty, int w0p, int tx) {
#pragma unroll
    for (int r = 0; r < RB; ++r) {
        f2 ol = pkfma(accl[r], bn.ivl, bn.shl);
        f2 oh = pkfma(acch[r], bn.ivh, bn.shh);
        float4 o;
        o.x = ol.x > 0.f ? ol.x : 0.f;
        o.y = ol.y > 0.f ? ol.y : 0.f;
        o.z = oh.x > 0.f ? oh.x : 0.f;
        o.w = oh.y > 0.f ? oh.y : 0.f;
        *reinterpret_cast<float4*>(
            out + ((((size_t)b * HH + h0 + ty * RB + r) * WW + w0p + tx) << 2)) = o;
    }
}

// pipelined multi-tile loop: ds_write(i) -> barrier -> issue loads(i+1) ->
// compute(i) -> store -> barrier.
template <int K, bool DW>
__device__ __forceinline__ void run_tiles(const float* __restrict__ x,
                                          float* __restrict__ out,
                                          const float* __restrict__ wgt,
                                          const BN& bn, float4* tile,
                                          int b, int h0b, int w0p,
                                          const int* tr, const int* tc,
                                          int t, int tx, int ty) {
    float4 pf[NSLOT];
    load_pf(x, b, h0b, w0p, tr, tc, t, pf);
#pragma unroll 1
    for (int i = 0; i < NT; ++i) {
        int h0 = h0b + i * TH;
#pragma unroll
        for (int j = 0; j < NSLOT; ++j) {
            if (j == NSLOT - 1 && t >= NTILE - 256 * (NSLOT - 1)) continue;
            tile[t + 256 * j] = pf[j];
        }
        __syncthreads();
        if (i + 1 < NT) load_pf(x, b, h0 + TH, w0p, tr, tc, t, pf);  // issue early
        f2 accl[RB] = {f2{0.f,0.f}, f2{0.f,0.f}, f2{0.f,0.f}, f2{0.f,0.f}};
        f2 acch[RB] = {f2{0.f,0.f}, f2{0.f,0.f}, f2{0.f,0.f}, f2{0.f,0.f}};
        conv_tile<K, DW>(tile, wgt, tx, ty, accl, acch);
        bn_store(out, bn, accl, acch, b, h0, ty, w0p, tx);
        __syncthreads();
    }
}

__global__ __launch_bounds__(256, 4) void mixop_kernel(
    const float* __restrict__ x,
    const float* __restrict__ logits, const float* __restrict__ g,
    const float* __restrict__ w0, const float* __restrict__ w1,
    const float* __restrict__ w2, const float* __restrict__ w3,
    const float* __restrict__ w4,
    const float* __restrict__ gamma, const float* __restrict__ beta,
    const float* __restrict__ mean, const float* __restrict__ var,
    float* __restrict__ out) {
    __shared__ float4 tile[NTILE];

    int t   = threadIdx.x;
    int blk = blockIdx.x;
    int bw  = blk & 7;             // WW/TW = 8
    int hg  = (blk >> 3) & 3;      // HH/(TH*NT) = 4
    int b   = blk >> 5;            // batch
    int w0p = bw * TW;
    int h0b = hg * (TH * NT);

    // wave-uniform routing: argmax(logits + g), first-max wins (s_load inputs)
    int idx = 0;
    float best = ldw1(logits + 0) + ldw1(g + 0);
#pragma unroll
    for (int i = 1; i < 5; ++i) {
        float v = ldw1(logits + i) + ldw1(g + i);
        if (v > best) { best = v; idx = i; }
    }

    int tx = t & 63;               // lane-consecutive w -> coalesced I/O
    int ty = t >> 6;

    BN bn = make_bn(gamma, beta, mean, var, idx);

    if (idx == 0) {
        // 1x1 conv: no reuse -> direct global reads, no LDS/barriers
        f2 a0 = ldw2(w0 + 0),  c0 = ldw2(w0 + 2);
        f2 a1 = ldw2(w0 + 4),  c1 = ldw2(w0 + 6);
        f2 a2 = ldw2(w0 + 8),  c2 = ldw2(w0 + 10);
        f2 a3 = ldw2(w0 + 12), c3 = ldw2(w0 + 14);
#pragma unroll 1
        for (int i = 0; i < NT; ++i) {
            int h0 = h0b + i * TH;
            f2 accl[RB], acch[RB];
#pragma unroll
            for (int r = 0; r < RB; ++r) {
                float4 p = ldx4(x, b, h0 + ty * RB + r, w0p + tx);
                f2 px = splat(p.x), py = splat(p.y);
                f2 pz = splat(p.z), pw = splat(p.w);
                accl[r] = px * a0;
                accl[r] = pkfma(py, a1, accl[r]);
                accl[r] = pkfma(pz, a2, accl[r]);
                accl[r] = pkfma(pw, a3, accl[r]);
                acch[r] = px * c0;
                acch[r] = pkfma(py, c1, acch[r]);
                acch[r] = pkfma(pz, c2, acch[r]);
                acch[r] = pkfma(pw, c3, acch[r]);
            }
            bn_store(out, bn, accl, acch, b, h0, ty, w0p, tx);
        }
        return;
    }

    // per-thread staging coords, computed once per block
    int tr[NSLOT], tc[NSLOT];
#pragma unroll
    for (int j = 0; j < NSLOT; ++j) {
        int k = t + 256 * j;
        tr[j] = k / TIW;
        tc[j] = k - tr[j] * TIW;
    }

    switch (idx) {
        case 1: run_tiles<3, false>(x, out, w1, bn, tile, b, h0b, w0p, tr, tc, t, tx, ty); break;
        case 2: run_tiles<3, true >(x, out, w2, bn, tile, b, h0b, w0p, tr, tc, t, tx, ty); break;
        case 3: run_tiles<5, false>(x, out, w3, bn, tile, b, h0b, w0p, tr, tc, t, tx, ty); break;
        case 4: run_tiles<5, true >(x, out, w4, bn, tile, b, h0b, w0p, tr, tc, t, tx, ty); break;
    }
}

extern "C" void kernel_launch(void* const* d_in, const int* in_sizes, int n_in,
                              void* d_out, int out_size, void* d_ws, size_t ws_size,
                              hipStream_t stream) {
    const float* x      = (const float*)d_in[0];
    const float* logits = (const float*)d_in[1];
    const float* g      = (const float*)d_in[2];
    const float* w0     = (const float*)d_in[3];
    const float* w1     = (const float*)d_in[4];
    const float* w2     = (const float*)d_in[5];
    const float* w3     = (const float*)d_in[6];
    const float* w4     = (const float*)d_in[7];
    const float* gamma  = (const float*)d_in[8];
    const float* beta   = (const float*)d_in[9];
    const float* mean   = (const float*)d_in[10];
    const float* var    = (const float*)d_in[11];
    float* out = (float*)d_out;

    const int blocks = NB * (WW / TW) * (HH / (TH * NT));  // 32*8*4 = 1024
    mixop_kernel<<<blocks, 256, 0, stream>>>(
        x, logits, g, w0, w1, w2, w3, w4, gamma, beta, mean, var, out);
}